// Round 2
// baseline (1183.131 us; speedup 1.0000x reference)
//
#include <hip/hip_runtime.h>

typedef __attribute__((ext_vector_type(4))) float floatx4;

#define NH 512             // HIDDEN
#define NB 512             // batch
#define TILE 256           // floats per 16x16 tile
#define BPW 32             // b's per wave
#define NGRP 8             // groups per wave, 4 tiles each
#define SLOTF 272          // floats per LDS slot: 1KB tile + 64B pad (bank-spread)

// Dense-load redesign. Old kernel: 17 VMEM instr/tile, each load replicated
// 16x across lanes (64B useful) -> 47 cyc/VMEM instr, 1.18 TB/s. New: wave
// handles 4 tiles/group; loads+stores are dense 1KB/instr (2 VMEM/tile);
// redistribution through wave-private LDS (no barriers needed -- DS ops are
// in-order within a wave). Register-staged global->LDS (T14) so the compiler
// tracks loads per-VGPR and emits counted vmcnt (pipelining survives).
//
// Lane = (t = tile 0..3, og = row-group 0..3, q = col-quad 0..3):
//   owns y rows og*4..og*4+3, cols q*4..q*4+3 of tile t.
// LDS slot stride 272 floats => ds_read bank = 16*((t+i)&1) + 4q : 2-way, free.
// ds_read_b128 x[i][quad]: 4-way same-address broadcast (og) = free.
__global__ __launch_bounds__(256, 3) void GlobalMixer_kernel(
    const float* __restrict__ x,
    const float* __restrict__ w,
    float* __restrict__ y)
{
    __shared__ float lds[4][4][SLOTF];   // [wave][tile slot][272]

    const int lane = threadIdx.x & 63;
    const int wv   = threadIdx.x >> 6;
    const int gid  = blockIdx.x * 4 + wv;   // 0..8191
    const int h    = gid & (NH - 1);
    const int b0   = (gid >> 9) * BPW;
    const int t    = lane >> 4;             // tile within group
    const int og   = (lane >> 2) & 3;       // output row group
    const int q    = lane & 3;              // col quad

    // ---- W rows og*4..og*4+3 of matrix h: 64 scalars in VGPRs (wave-lifetime)
    float wreg[4][16];
    {
        const float* wp = w + h * TILE + (og * 4) * 16;
        #pragma unroll
        for (int j = 0; j < 4; ++j)
            #pragma unroll
            for (int i4 = 0; i4 < 4; ++i4) {
                floatx4 wq = *(const floatx4*)(wp + j * 16 + i4 * 4);
                wreg[j][i4 * 4 + 0] = wq.x; wreg[j][i4 * 4 + 1] = wq.y;
                wreg[j][i4 * 4 + 2] = wq.z; wreg[j][i4 * 4 + 3] = wq.w;
            }
    }

    const size_t bstride = (size_t)NH * TILE;    // floats between b's

    // per-lane global pointers
    const float* xl = x + ((size_t)b0 * NH + h) * TILE + lane * 4;          // loads
    float*       yg = y + ((size_t)(b0 + t) * NH + h) * TILE + og * 64 + q * 4; // stores

    float*       ldsw = &lds[wv][0][0];   // + k*SLOTF + lane*4
    const float* ldsr = &lds[wv][t][0];   // + i*16 + q*4

    floatx4 sA[4], sB[4];

    // prologue: group 0 dense loads (tile = b0+k, each lane a distinct float4)
    #pragma unroll
    for (int k = 0; k < 4; ++k)
        sA[k] = *(const floatx4*)(xl + (size_t)k * bstride);

    const float* xg = xl + 4 * bstride;   // next group's load base

    auto body = [&](floatx4* cur, floatx4* nxt, bool prefetch) {
        // issue next group's dense loads first (hide HBM latency under compute)
        if (prefetch) {
            #pragma unroll
            for (int k = 0; k < 4; ++k)
                nxt[k] = *(const floatx4*)(xg + (size_t)k * bstride);
            xg += 4 * bstride;
        }
        // stage current group to LDS (compiler: counted vmcnt on cur[k])
        #pragma unroll
        for (int k = 0; k < 4; ++k)
            *(floatx4*)(ldsw + k * SLOTF + lane * 4) = cur[k];
        // compute: 4 output rows x col-quad, K=16
        floatx4 acc0 = {0.f,0.f,0.f,0.f}, acc1 = {0.f,0.f,0.f,0.f};
        floatx4 acc2 = {0.f,0.f,0.f,0.f}, acc3 = {0.f,0.f,0.f,0.f};
        #pragma unroll
        for (int i = 0; i < 16; ++i) {
            floatx4 xv = *(const floatx4*)(ldsr + i * 16 + q * 4);
            acc0 += wreg[0][i] * xv;
            acc1 += wreg[1][i] * xv;
            acc2 += wreg[2][i] * xv;
            acc3 += wreg[3][i] * xv;
        }
        // dense stores: 4 x 1KB (row og*4+j, all (t,og,q) distinct)
        *(floatx4*)(yg + 0 * 16) = acc0;
        *(floatx4*)(yg + 1 * 16) = acc1;
        *(floatx4*)(yg + 2 * 16) = acc2;
        *(floatx4*)(yg + 3 * 16) = acc3;
        yg += 4 * bstride;
    };

    // 8 groups, double-buffered: bodies 0..6 prefetch, body 7 doesn't
    for (int g = 0; g < NGRP - 2; g += 2) {
        body(sA, sB, true);
        body(sB, sA, true);
    }
    body(sA, sB, true);
    body(sB, sA, false);
}

extern "C" void kernel_launch(void* const* d_in, const int* in_sizes, int n_in,
                              void* d_out, int out_size, void* d_ws, size_t ws_size,
                              hipStream_t stream) {
    const float* x = (const float*)d_in[0];   // (512, 512, 1, 256) fp32
    const float* w = (const float*)d_in[1];   // (512, 16, 16) fp32
    float*       y = (float*)d_out;           // (512, 512, 1, 256) fp32

    dim3 grid(2048), block(256);
    hipLaunchKernelGGL(GlobalMixer_kernel, grid, block, 0, stream, x, w, y);
}